// Round 1
// baseline (1144.810 us; speedup 1.0000x reference)
//
#include <hip/hip_runtime.h>
#include <hip/hip_bf16.h>
#include <stdint.h>

#define KTOP 5

// ---------------------------------------------------------------------------
// Pre-pass: labels[p] = argmax_c oh[p*C + c]   (one-hot -> int label)
// ---------------------------------------------------------------------------
__global__ void label_kernel(const float* __restrict__ oh,
                             int* __restrict__ labels, int P, int C) {
    int p = blockIdx.x * blockDim.x + threadIdx.x;
    if (p >= P) return;
    const float* row = oh + (size_t)p * C;
    int lab = 0;
    float best = row[0];
    for (int c = 1; c < C; ++c) {
        float v = row[c];
        if (v > best) { best = v; lab = c; }
    }
    labels[p] = lab;
}

// ---------------------------------------------------------------------------
// Main: one block per row. Strided float4 scan, per-thread sorted top-5 of
// 64-bit keys (value_bits<<32 | index)  -> LDS merge tree -> vote.
// Key ordering == (value asc, index asc), matching lax.top_k tie-break.
// ---------------------------------------------------------------------------
__global__ __launch_bounds__(256)
void knn_kernel(const float* __restrict__ x, const int* __restrict__ labels,
                int* __restrict__ out, int P) {
    const int row = blockIdx.x;
    const int tid = threadIdx.x;

    const float* xrow = x + (size_t)row * P;

    unsigned long long t[KTOP];
#pragma unroll
    for (int m = 0; m < KTOP; ++m) t[m] = 0xFFFFFFFFFFFFFFFFULL;

    auto ins = [&](float v, int idx) {
        unsigned long long key =
            ((unsigned long long)__float_as_uint(v) << 32) | (unsigned int)idx;
        if (key < t[KTOP - 1]) {
            t[KTOP - 1] = key;
#pragma unroll
            for (int m = KTOP - 1; m > 0; --m) {
                if (t[m] < t[m - 1]) {
                    unsigned long long tmp = t[m];
                    t[m] = t[m - 1];
                    t[m - 1] = tmp;
                }
            }
        }
    };

    // Vectorized body (rows are 16B-aligned when P % 4 == 0).
    const int nvec = P >> 2;
    const float4* rowp = (const float4*)xrow;
    for (int i = tid; i < nvec; i += 256) {
        float4 v = rowp[i];
        int base = i << 2;
        ins(v.x, base + 0);
        ins(v.y, base + 1);
        ins(v.z, base + 2);
        ins(v.w, base + 3);
    }
    // Scalar tail (P % 4 != 0).
    for (int idx = (nvec << 2) + tid; idx < P; idx += 256) ins(xrow[idx], idx);

    // ---- LDS merge tree: 256 sorted 5-lists -> 1 ----
    __shared__ unsigned long long s[256 * KTOP];
#pragma unroll
    for (int m = 0; m < KTOP; ++m) s[tid * KTOP + m] = t[m];
    __syncthreads();

    for (int stride = 128; stride >= 1; stride >>= 1) {
        if (tid < stride) {
            unsigned long long* a = &s[tid * KTOP];
            unsigned long long* b = &s[(tid + stride) * KTOP];
            unsigned long long merged[KTOP];
            int i = 0, j = 0;
#pragma unroll
            for (int m = 0; m < KTOP; ++m) {
                bool takeA = (j >= KTOP) || (i < KTOP && a[i] <= b[j]);
                merged[m] = takeA ? a[i++] : b[j++];
            }
#pragma unroll
            for (int m = 0; m < KTOP; ++m) a[m] = merged[m];
        }
        __syncthreads();
    }

    // ---- Vote (thread 0): count labels of the 5 nearest, argmax with
    // lowest-class-index tie-break (matches jnp.argmax semantics). ----
    if (tid == 0) {
        int labs[KTOP];
#pragma unroll
        for (int m = 0; m < KTOP; ++m) {
            int idx = (int)(s[m] & 0xFFFFFFFFULL);
            labs[m] = labels[idx];
        }
        int bestLab = 0x7FFFFFFF, bestCnt = 0;
#pragma unroll
        for (int m = 0; m < KTOP; ++m) {
            int cnt = 0;
#pragma unroll
            for (int n = 0; n < KTOP; ++n) cnt += (labs[n] == labs[m]) ? 1 : 0;
            if (cnt > bestCnt || (cnt == bestCnt && labs[m] < bestLab)) {
                bestCnt = cnt;
                bestLab = labs[m];
            }
        }
        out[row] = bestLab;
    }
}

// ---------------------------------------------------------------------------
extern "C" void kernel_launch(void* const* d_in, const int* in_sizes, int n_in,
                              void* d_out, int out_size, void* d_ws,
                              size_t ws_size, hipStream_t stream) {
    const float* x = (const float*)d_in[0];
    const float* oh = (const float*)d_in[1];
    // (d_in[2] is k == 5; KTOP hardcoded)

    const int B = out_size;                    // 4096
    const int P = (int)(in_sizes[0] / B);      // 50000
    const int C = (int)(in_sizes[1] / P);      // 100

    int* labels = (int*)d_ws;                  // P ints of scratch
    int* out = (int*)d_out;

    label_kernel<<<(P + 255) / 256, 256, 0, stream>>>(oh, labels, P, C);
    knn_kernel<<<B, 256, 0, stream>>>(x, labels, out, P);
}